// Round 19
// baseline (160.192 us; speedup 1.0000x reference)
//
#include <hip/hip_runtime.h>

typedef unsigned short ushort_t;
typedef unsigned int u32;
typedef short bf16x8 __attribute__((ext_vector_type(8)));
typedef float f32x4 __attribute__((ext_vector_type(4)));
typedef u32 u32x4 __attribute__((ext_vector_type(4)));

__device__ __forceinline__ float bf2f(ushort_t u) {
    u32 x = ((u32)u) << 16; float f; __builtin_memcpy(&f, &x, 4); return f;
}
__device__ __forceinline__ ushort_t f2bf(float f) {
    u32 x; __builtin_memcpy(&x, &f, 4);
    x = x + 0x7fffu + ((x >> 16) & 1u);
    return (ushort_t)(x >> 16);
}

#define NBB 128                       /* base rows per block */
#define UROWS 136                     /* NBB + 8 halo */
#define USTRB 208                     /* bytes per U row (96 bf16 + pad) */
#define UB_BYTES (UROWS * USTRB)      /* 28288 */
#define LDS_TOTAL UB_BYTES
#define LSTR1 261                     /* stage1 epilogue f32 row stride (odd) */

// ---------- prepA: fold unpool+mask -> Wplain [st][k][cc][o]  +  ADD tables ----
__global__ void prepA(const float* __restrict__ w0, const float* __restrict__ m0,
                      const float* __restrict__ w1, const float* __restrict__ m1,
                      const float* __restrict__ offw0, const float* __restrict__ offb0,
                      const float* __restrict__ omask0, const float* __restrict__ convb0,
                      const float* __restrict__ off0,
                      const float* __restrict__ offw1, const float* __restrict__ offb1,
                      const float* __restrict__ omask1, const float* __restrict__ convb1,
                      const float* __restrict__ off1,
                      float* __restrict__ Wplain, float* __restrict__ ADD0,
                      float* __restrict__ ADD1)
{
    int idx = blockIdx.x * 64 + threadIdx.x;
    if (idx < 18432) {                        // 2st x 96cc x 96o, o fastest
        int o = idx % 96;
        int cc = (idx / 96) % 96;
        int st = idx / 9216;
        const float* w = st ? w1 : w0;
        const float* mk = st ? m1 : m0;
        int cpj = st ? 8 : 16;
        int i = cc / cpj, c = cc % cpj;
        float s[15];
#pragma unroll
        for (int k = 0; k < 15; ++k) s[k] = 0.f;
#pragma unroll
        for (int d = 0; d < 2; ++d) {
            int f = (2 * i + d) * cpj + c;
            int base = (o * 192 + f) * 15;
#pragma unroll
            for (int k = 0; k < 15; ++k)
                s[k] += w[base + k] * mk[base + k];
        }
#pragma unroll
        for (int k = 0; k < 15; ++k)
            Wplain[st * 138240 + (k * 96 + cc) * 96 + o] = s[k];
    } else if (idx < 18432 + 12288) {
        int a = idx - 18432;
        int st = a / 6144; int a2 = a % 6144;
        int o = a2 % 96, b = a2 / 96;
        const float* ow = st ? offw1 : offw0;
        const float* ob = st ? offb1 : offb0;
        const float* om = st ? omask1 : omask0;
        const float* cb = st ? convb1 : convb0;
        const float* of = st ? off1 : off0;
        int J = st ? 72 : 36;
        float s = 0.f;
        for (int j2 = 0; j2 < J; ++j2) s += ow[o * J + j2] * om[o * J + j2] * of[b * J + j2];
        (st ? ADD1 : ADD0)[b * 96 + o] = cb[o] + (s + ob[o]) * 0.01f;
    }
}

// ---------- wide boundary dot-products (shared body), lane = o (coalesced) -----
template<int BF16SRC>
__device__ __forceinline__ void gbody(int idx, const float* __restrict__ WP,
                                      const float* __restrict__ srcF,
                                      const ushort_t* __restrict__ srcB,
                                      float* __restrict__ G, int T)
{
    if (idx >= 184320) return;                // 64b x 2side x 15k x 96o
    int o = idx % 96; int t = idx / 96;
    int k = t % 15; t /= 15;
    int side = t % 2; int b = t / 2;
    const float* wk = WP + (size_t)k * 9216 + o;
    int row = side ? T - 1 : 0;
    float s = 0.f;
    if (BF16SRC) {
        const ushort_t* xr = srcB + ((size_t)b * T + row) * 96;
        for (int cc = 0; cc < 96; ++cc)
            s += wk[cc * 96] * bf2f(xr[cc]);
    } else {
        const float* xr = srcF + ((size_t)b * T + row) * 96;
        for (int cc = 0; cc < 96; ++cc)
            s += wk[cc * 96] * bf2f(f2bf(xr[cc]));
    }
    G[((size_t)(b * 96 + o) * 15 + k) * 2 + side] = s;
}

// ---------- prepBG: polyphase A-frag weights + stage0 G (merged, both wide) ----
__global__ void prepBG(const float* __restrict__ Wplain,
                       ushort_t* __restrict__ Wp0, ushort_t* __restrict__ Wp1,
                       const float* __restrict__ x, float* __restrict__ G0)
{
    if (blockIdx.x >= 1296) {                 // 720 blocks: stage0 G
        gbody<0>((blockIdx.x - 1296) * 256 + threadIdx.x, Wplain, x, nullptr, G0, 1024);
        return;
    }
    int idx = blockIdx.x * 256 + threadIdx.x;
    if (idx >= 331776) return;                // 2st x 2p x 9j x 96cc x 96o
    int o = idx % 96; int t = idx / 96;
    int cc = t % 96; t /= 96;
    int j = t % 9; t /= 9;
    int p = t % 2; int st = t / 2;
    const float* WP = Wplain + (size_t)st * 138240;
    int kk[4]; float cf[4];
    if (p == 0) { kk[0]=2*j;   cf[0]=0.75f; kk[1]=2*j-2; cf[1]=0.25f;
                  kk[2]=2*j+1; cf[2]=0.25f; kk[3]=2*j-1; cf[3]=0.75f; }
    else        { kk[0]=2*j;   cf[0]=0.25f; kk[1]=2*j-2; cf[1]=0.75f;
                  kk[2]=2*j-1; cf[2]=0.75f; kk[3]=2*j-3; cf[3]=0.25f; }
    float s = 0.f;
#pragma unroll
    for (int q = 0; q < 4; ++q) {
        int k = kk[q];
        if (k >= 0 && k < 15) s += cf[q] * WP[(k * 96 + cc) * 96 + o];
    }
    int lane = (o & 15) | (((cc >> 3) & 3) << 4);
    int mh = (o >> 4) / 3, m = (o >> 4) % 3;
    int pos = ((((j * 2 + mh) * 2 + p) * 9) + (cc >> 5) * 3 + m) * 512 + lane * 8 + (cc & 7);
    (st ? Wp1 : Wp0)[pos] = f2bf(s);
}

// ---------- prep_G1: stage1 boundary dot-products from H1 ----------
__global__ void prep_G1(const float* __restrict__ WP, const ushort_t* __restrict__ H1,
                        float* __restrict__ G)
{
    gbody<1>(blockIdx.x * 256 + threadIdx.x, WP, nullptr, H1, G, 2048);
}

// ---------- prep_cfb: prefix sums of G -> CF/CB ----------
__global__ void prep_cfb(const float* __restrict__ G, float* __restrict__ CF,
                         float* __restrict__ CB)
{
    int idx = blockIdx.x * 256 + threadIdx.x;
    if (idx >= 86016) return;                 // 64 x 96 x 14
    int seg = idx % 14; int r = idx / 14;
    int o = r % 96; int b = r / 96;
    bool front = seg < 7; int t = front ? seg : seg - 7;
    float s = 0.f;
    if (front) { for (int k = 0; k <= 6 - t; ++k)   s += G[(((size_t)(b*96+o)*15)+k)*2 + 0]; }
    else       { for (int k = 14 - t; k <= 14; ++k) s += G[(((size_t)(b*96+o)*15)+k)*2 + 1]; }
    (front ? CF : CB)[(b * 7 + t) * 96 + o] = s;
}

// ---------- fused polyphase conv (r18 body; launch_bounds 4->5 blocks/CU) -----
template<int STAGE>
__launch_bounds__(256, 5)
__global__ void conv_poly(const float* __restrict__ Xf, const ushort_t* __restrict__ Hbf,
                          const ushort_t* __restrict__ Wp, const float* __restrict__ ADD,
                          const float* __restrict__ CF, const float* __restrict__ CB,
                          ushort_t* __restrict__ Hout, float* __restrict__ Fout, int T)
{
    extern __shared__ char smem[];
    char* Ub = smem;

    const int tid = threadIdx.x;
    const int lane = tid & 63;
    const int wid = tid >> 6;         // 0..3
    const int flat = blockIdx.x;
    const int chunk = gridDim.x >> 3;
    const int wf = (flat & 7) * chunk + (flat >> 3);
    const int tgmhN = (STAGE == 0) ? 16 : 32;
    const int tgmh = wf % tgmhN;
    const int b = wf / tgmhN;
    const int tg = tgmh >> 1;
    const int mh = tgmh & 1;          // output-channel half
    const int phase = wid & 1;
    const int nq = wid >> 1;          // 0..1, 64 base rows each
    const int rb0 = tg * NBB - 4;

    const ushort_t* wgl = Wp + (size_t)(mh * 2 + phase) * 4608 + lane * 8;

    // stage U at base rate, clamped rows (plain layout, no swizzle)
    if (STAGE == 0) {
        const float* xb = Xf + (size_t)b * T * 96;
        for (int idx = tid; idx < UROWS * 12; idx += 256) {
            int r = idx / 12, q = idx - r * 12;
            int rg = rb0 + r; rg = rg < 0 ? 0 : (rg > T - 1 ? T - 1 : rg);
            const float* src = xb + (size_t)rg * 96 + q * 8;
            float4 a = *(const float4*)src;
            float4 c2 = *(const float4*)(src + 4);
            u32x4 v;
            v[0] = (u32)f2bf(a.x) | ((u32)f2bf(a.y) << 16);
            v[1] = (u32)f2bf(a.z) | ((u32)f2bf(a.w) << 16);
            v[2] = (u32)f2bf(c2.x) | ((u32)f2bf(c2.y) << 16);
            v[3] = (u32)f2bf(c2.z) | ((u32)f2bf(c2.w) << 16);
            *(u32x4*)(Ub + r * USTRB + q * 16) = v;
        }
    } else {
        const ushort_t* xb = Hbf + (size_t)b * T * 96;
        for (int idx = tid; idx < UROWS * 12; idx += 256) {
            int r = idx / 12, q = idx - r * 12;
            int rg = rb0 + r; rg = rg < 0 ? 0 : (rg > T - 1 ? T - 1 : rg);
            u32x4 v = *(const u32x4*)(xb + (size_t)rg * 96 + q * 8);
            *(u32x4*)(Ub + r * USTRB + q * 16) = v;
        }
    }
    __syncthreads();

    f32x4 acc[3][4];
#pragma unroll
    for (int m = 0; m < 3; ++m)
#pragma unroll
        for (int n = 0; n < 4; ++n) acc[m][n] = (f32x4){0.f, 0.f, 0.f, 0.f};

    const int rowbase = 64 * nq + (lane & 15);
    const int og16 = (lane >> 4) * 16;

#pragma unroll
    for (int j = 0; j < 9; ++j) {
        const ushort_t* wj = wgl + (size_t)j * 18432;
        bf16x8 aj[9];
#pragma unroll
        for (int q = 0; q < 9; ++q)
            aj[q] = *(const bf16x8*)(wj + q * 512);

        const int bj = (rowbase + j) * USTRB;
#pragma unroll
        for (int cb = 0; cb < 3; ++cb) {
            const int off0 = bj + cb * 64 + og16;
            bf16x8 bfr[4];
#pragma unroll
            for (int n = 0; n < 4; ++n)
                bfr[n] = *(const bf16x8*)(Ub + off0 + n * 16 * USTRB);
            __builtin_amdgcn_s_setprio(1);
#pragma unroll
            for (int m = 0; m < 3; ++m)
#pragma unroll
                for (int n = 0; n < 4; ++n)
                    acc[m][n] = __builtin_amdgcn_mfma_f32_16x16x32_bf16(aj[cb * 3 + m], bfr[n], acc[m][n], 0, 0, 0);
            __builtin_amdgcn_s_setprio(0);
        }
    }

    // ---------------- epilogue: LDS transpose -> coalesced stores --------------
    const int T2 = 2 * T;
    const int t0 = tg * 2 * NBB;          // 256 output t per block
    const int og4 = (lane >> 4) * 4;

    __syncthreads();   // all B-frag reads done before Ub reuse

    if (STAGE == 0) {
        ushort_t* L0 = (ushort_t*)Ub;     // [256 t][48 ch] bf16, stride 104 B
#pragma unroll
        for (int m = 0; m < 3; ++m) {
            int obase = mh * 48 + m * 16 + og4;
            float addv[4];
#pragma unroll
            for (int rr = 0; rr < 4; ++rr) addv[rr] = ADD[b * 96 + obase + rr];
#pragma unroll
            for (int n = 0; n < 4; ++n) {
                int tl = 2 * (rowbase + 16 * n) + phase;   // 0..255
                int tgl = t0 + tl;
                ushort_t pk[4];
#pragma unroll
                for (int rr = 0; rr < 4; ++rr) {
                    float v = acc[m][n][rr] + addv[rr];
                    if (tgl < 7)                   v -= CF[(b * 7 + tgl) * 96 + obase + rr];
                    if (tgl >= T2 - 7 && tgl < T2) v -= CB[(b * 7 + tgl - (T2 - 7)) * 96 + obase + rr];
                    v = v > 0.f ? v : 0.2f * v;
                    pk[rr] = f2bf(v);
                }
                uint2 w2;
                w2.x = (u32)pk[0] | ((u32)pk[1] << 16);
                w2.y = (u32)pk[2] | ((u32)pk[3] << 16);
                *(uint2*)((char*)L0 + tl * 104 + (m * 16 + og4) * 2) = w2;
            }
        }
        __syncthreads();
        for (int g = tid; g < 256 * 6; g += 256) {   // 256 t x 6 seg of 16 B
            int row = g / 6, col = g % 6;
            int t = t0 + row;
            if (t < T2) {
                u32x4 v = *(const u32x4*)((char*)L0 + row * 104 + col * 16);
                *(u32x4*)((char*)Hout + ((size_t)(b * T2 + t) * 96 + mh * 48) * 2 + col * 16) = v;
            }
        }
    } else {
        const int TO = T2 - 1;            // 4095
        float* L1 = (float*)Ub;           // [16 o][LSTR1 f32] per m-chunk
#pragma unroll
        for (int m = 0; m < 3; ++m) {
            int obase = mh * 48 + m * 16 + og4;
            float addv[4];
#pragma unroll
            for (int rr = 0; rr < 4; ++rr) addv[rr] = ADD[b * 96 + obase + rr];
#pragma unroll
            for (int n = 0; n < 4; ++n) {
                int tl = 2 * (rowbase + 16 * n) + phase;
                int tgl = t0 + tl;
#pragma unroll
                for (int rr = 0; rr < 4; ++rr) {
                    float v = acc[m][n][rr] + addv[rr];
                    if (tgl < 7)                   v -= CF[(b * 7 + tgl) * 96 + obase + rr];
                    if (tgl >= T2 - 7 && tgl < T2) v -= CB[(b * 7 + tgl - (T2 - 7)) * 96 + obase + rr];
                    L1[(og4 + rr) * LSTR1 + tl] = v;
                }
            }
            __syncthreads();
            for (int g = tid; g < 4096; g += 256) {  // 16 o-rows x 256 cols
                int row = g >> 8, col = g & 255;
                int t = t0 + col;
                if (t < TO) {
                    int o_g = mh * 48 + m * 16 + row;
                    Fout[((size_t)(b * 96 + o_g)) * TO + t] = L1[row * LSTR1 + col];
                }
            }
            __syncthreads();
        }
    }
}

extern "C" void kernel_launch(void* const* d_in, const int* in_sizes, int n_in,
                              void* d_out, int out_size, void* d_ws, size_t ws_size,
                              hipStream_t stream)
{
    const float* x       = (const float*)d_in[0];
    const float* offset0 = (const float*)d_in[1];
    const float* offset1 = (const float*)d_in[2];
    const float* conv_w0 = (const float*)d_in[5];
    const float* conv_b0 = (const float*)d_in[6];
    const float* conv_w1 = (const float*)d_in[7];
    const float* conv_b1 = (const float*)d_in[8];
    const float* off_w0  = (const float*)d_in[9];
    const float* off_b0  = (const float*)d_in[10];
    const float* off_w1  = (const float*)d_in[11];
    const float* off_b1  = (const float*)d_in[12];
    const float* cmask0  = (const float*)d_in[13];
    const float* cmask1  = (const float*)d_in[14];
    const float* omask0  = (const float*)d_in[15];
    const float* omask1  = (const float*)d_in[16];

    char* ws = (char*)d_ws;
    float*    Wplain = (float*)(ws);                  // 1,105,920
    ushort_t* Wp0    = (ushort_t*)(ws + 1105920);     // 331,776
    ushort_t* Wp1    = (ushort_t*)(ws + 1437696);     // 331,776
    float*    ADD0   = (float*)(ws + 1769472);        // 24,576
    float*    ADD1   = (float*)(ws + 1794048);        // 24,576
    float*    CF0    = (float*)(ws + 1818624);        // 172,032
    float*    CB0    = (float*)(ws + 1990656);        // 172,032
    float*    CF1    = (float*)(ws + 2162688);        // 172,032
    float*    CB1    = (float*)(ws + 2334720);        // 172,032
    float*    G0     = (float*)(ws + 2506752);        // 737,280
    float*    G1     = (float*)(ws + 3244032);        // 737,280
    ushort_t* H1     = (ushort_t*)(ws + 3981312);     // 25,165,824
    float* out = (float*)d_out;

    prepA<<<480, 64, 0, stream>>>(conv_w0, cmask0, conv_w1, cmask1,
                                  off_w0, off_b0, omask0, conv_b0, offset0,
                                  off_w1, off_b1, omask1, conv_b1, offset1,
                                  Wplain, ADD0, ADD1);
    prepBG<<<2016, 256, 0, stream>>>(Wplain, Wp0, Wp1, x, G0);
    prep_cfb<<<336, 256, 0, stream>>>(G0, CF0, CB0);

    conv_poly<0><<<1024, 256, LDS_TOTAL, stream>>>(x, nullptr, Wp0, ADD0, CF0, CB0,
                                                   H1, nullptr, 1024);
    prep_G1<<<720, 256, 0, stream>>>(Wplain + 138240, H1, G1);
    prep_cfb<<<336, 256, 0, stream>>>(G1, CF1, CB1);
    conv_poly<1><<<2048, 256, LDS_TOTAL, stream>>>(nullptr, H1, Wp1, ADD1, CF1, CB1,
                                                   nullptr, out, 2048);
}

// Round 20
// 113.737 us; speedup vs baseline: 1.4084x; 1.4084x over previous
//
#include <hip/hip_runtime.h>

typedef unsigned short ushort_t;
typedef unsigned int u32;
typedef short bf16x8 __attribute__((ext_vector_type(8)));
typedef float f32x4 __attribute__((ext_vector_type(4)));
typedef u32 u32x4 __attribute__((ext_vector_type(4)));

__device__ __forceinline__ float bf2f(ushort_t u) {
    u32 x = ((u32)u) << 16; float f; __builtin_memcpy(&f, &x, 4); return f;
}
__device__ __forceinline__ ushort_t f2bf(float f) {
    u32 x; __builtin_memcpy(&x, &f, 4);
    x = x + 0x7fffu + ((x >> 16) & 1u);
    return (ushort_t)(x >> 16);
}

#define NBB 128                       /* base rows per block */
#define UROWS 136                     /* NBB + 8 halo */
#define USTRB 208                     /* bytes per U row (96 bf16 + pad) */
#define UB_BYTES (UROWS * USTRB)      /* 28288 */
#define LDS_TOTAL UB_BYTES
#define LSTR1 261                     /* stage1 epilogue f32 row stride (odd) */

// ---------- prepA: fold unpool+mask -> Wplain [st][k][cc][o]  +  ADD tables ----
__global__ void prepA(const float* __restrict__ w0, const float* __restrict__ m0,
                      const float* __restrict__ w1, const float* __restrict__ m1,
                      const float* __restrict__ offw0, const float* __restrict__ offb0,
                      const float* __restrict__ omask0, const float* __restrict__ convb0,
                      const float* __restrict__ off0,
                      const float* __restrict__ offw1, const float* __restrict__ offb1,
                      const float* __restrict__ omask1, const float* __restrict__ convb1,
                      const float* __restrict__ off1,
                      float* __restrict__ Wplain, float* __restrict__ ADD0,
                      float* __restrict__ ADD1)
{
    int idx = blockIdx.x * 64 + threadIdx.x;
    if (idx < 18432) {                        // 2st x 96cc x 96o, o fastest
        int o = idx % 96;
        int cc = (idx / 96) % 96;
        int st = idx / 9216;
        const float* w = st ? w1 : w0;
        const float* mk = st ? m1 : m0;
        int cpj = st ? 8 : 16;
        int i = cc / cpj, c = cc % cpj;
        float s[15];
#pragma unroll
        for (int k = 0; k < 15; ++k) s[k] = 0.f;
#pragma unroll
        for (int d = 0; d < 2; ++d) {
            int f = (2 * i + d) * cpj + c;
            int base = (o * 192 + f) * 15;
#pragma unroll
            for (int k = 0; k < 15; ++k)
                s[k] += w[base + k] * mk[base + k];
        }
#pragma unroll
        for (int k = 0; k < 15; ++k)
            Wplain[st * 138240 + (k * 96 + cc) * 96 + o] = s[k];
    } else if (idx < 18432 + 12288) {
        int a = idx - 18432;
        int st = a / 6144; int a2 = a % 6144;
        int o = a2 % 96, b = a2 / 96;
        const float* ow = st ? offw1 : offw0;
        const float* ob = st ? offb1 : offb0;
        const float* om = st ? omask1 : omask0;
        const float* cb = st ? convb1 : convb0;
        const float* of = st ? off1 : off0;
        int J = st ? 72 : 36;
        float s = 0.f;
        for (int j2 = 0; j2 < J; ++j2) s += ow[o * J + j2] * om[o * J + j2] * of[b * J + j2];
        (st ? ADD1 : ADD0)[b * 96 + o] = cb[o] + (s + ob[o]) * 0.01f;
    }
}

// ---------- wide boundary dot-products (shared body), lane = o (coalesced) -----
template<int BF16SRC>
__device__ __forceinline__ void gbody(int idx, const float* __restrict__ WP,
                                      const float* __restrict__ srcF,
                                      const ushort_t* __restrict__ srcB,
                                      float* __restrict__ G, int T)
{
    if (idx >= 184320) return;                // 64b x 2side x 15k x 96o
    int o = idx % 96; int t = idx / 96;
    int k = t % 15; t /= 15;
    int side = t % 2; int b = t / 2;
    const float* wk = WP + (size_t)k * 9216 + o;
    int row = side ? T - 1 : 0;
    float s = 0.f;
    if (BF16SRC) {
        const ushort_t* xr = srcB + ((size_t)b * T + row) * 96;
        for (int cc = 0; cc < 96; ++cc)
            s += wk[cc * 96] * bf2f(xr[cc]);
    } else {
        const float* xr = srcF + ((size_t)b * T + row) * 96;
        for (int cc = 0; cc < 96; ++cc)
            s += wk[cc * 96] * bf2f(f2bf(xr[cc]));
    }
    G[((size_t)(b * 96 + o) * 15 + k) * 2 + side] = s;
}

// ---------- prepBG: polyphase A-frag weights + stage0 G (merged, both wide) ----
__global__ void prepBG(const float* __restrict__ Wplain,
                       ushort_t* __restrict__ Wp0, ushort_t* __restrict__ Wp1,
                       const float* __restrict__ x, float* __restrict__ G0)
{
    if (blockIdx.x >= 1296) {                 // 720 blocks: stage0 G
        gbody<0>((blockIdx.x - 1296) * 256 + threadIdx.x, Wplain, x, nullptr, G0, 1024);
        return;
    }
    int idx = blockIdx.x * 256 + threadIdx.x;
    if (idx >= 331776) return;                // 2st x 2p x 9j x 96cc x 96o
    int o = idx % 96; int t = idx / 96;
    int cc = t % 96; t /= 96;
    int j = t % 9; t /= 9;
    int p = t % 2; int st = t / 2;
    const float* WP = Wplain + (size_t)st * 138240;
    int kk[4]; float cf[4];
    if (p == 0) { kk[0]=2*j;   cf[0]=0.75f; kk[1]=2*j-2; cf[1]=0.25f;
                  kk[2]=2*j+1; cf[2]=0.25f; kk[3]=2*j-1; cf[3]=0.75f; }
    else        { kk[0]=2*j;   cf[0]=0.25f; kk[1]=2*j-2; cf[1]=0.75f;
                  kk[2]=2*j-1; cf[2]=0.75f; kk[3]=2*j-3; cf[3]=0.25f; }
    float s = 0.f;
#pragma unroll
    for (int q = 0; q < 4; ++q) {
        int k = kk[q];
        if (k >= 0 && k < 15) s += cf[q] * WP[(k * 96 + cc) * 96 + o];
    }
    int lane = (o & 15) | (((cc >> 3) & 3) << 4);
    int mh = (o >> 4) / 3, m = (o >> 4) % 3;
    int pos = ((((j * 2 + mh) * 2 + p) * 9) + (cc >> 5) * 3 + m) * 512 + lane * 8 + (cc & 7);
    (st ? Wp1 : Wp0)[pos] = f2bf(s);
}

// ---------- prep_G1: stage1 boundary dot-products from H1 ----------
__global__ void prep_G1(const float* __restrict__ WP, const ushort_t* __restrict__ H1,
                        float* __restrict__ G)
{
    gbody<1>(blockIdx.x * 256 + threadIdx.x, WP, nullptr, H1, G, 2048);
}

// ---------- prep_cfb: prefix sums of G -> CF/CB ----------
__global__ void prep_cfb(const float* __restrict__ G, float* __restrict__ CF,
                         float* __restrict__ CB)
{
    int idx = blockIdx.x * 256 + threadIdx.x;
    if (idx >= 86016) return;                 // 64 x 96 x 14
    int seg = idx % 14; int r = idx / 14;
    int o = r % 96; int b = r / 96;
    bool front = seg < 7; int t = front ? seg : seg - 7;
    float s = 0.f;
    if (front) { for (int k = 0; k <= 6 - t; ++k)   s += G[(((size_t)(b*96+o)*15)+k)*2 + 0]; }
    else       { for (int k = 14 - t; k <= 14; ++k) s += G[(((size_t)(b*96+o)*15)+k)*2 + 1]; }
    (front ? CF : CB)[(b * 7 + t) * 96 + o] = s;
}

// ---------- fused polyphase conv (r18 verbatim: XCD grid + setprio, LB(256,4)) -
template<int STAGE>
__launch_bounds__(256, 4)
__global__ void conv_poly(const float* __restrict__ Xf, const ushort_t* __restrict__ Hbf,
                          const ushort_t* __restrict__ Wp, const float* __restrict__ ADD,
                          const float* __restrict__ CF, const float* __restrict__ CB,
                          ushort_t* __restrict__ Hout, float* __restrict__ Fout, int T)
{
    extern __shared__ char smem[];
    char* Ub = smem;

    const int tid = threadIdx.x;
    const int lane = tid & 63;
    const int wid = tid >> 6;         // 0..3
    const int flat = blockIdx.x;
    const int chunk = gridDim.x >> 3;
    const int wf = (flat & 7) * chunk + (flat >> 3);
    const int tgmhN = (STAGE == 0) ? 16 : 32;
    const int tgmh = wf % tgmhN;
    const int b = wf / tgmhN;
    const int tg = tgmh >> 1;
    const int mh = tgmh & 1;          // output-channel half
    const int phase = wid & 1;
    const int nq = wid >> 1;          // 0..1, 64 base rows each
    const int rb0 = tg * NBB - 4;

    const ushort_t* wgl = Wp + (size_t)(mh * 2 + phase) * 4608 + lane * 8;

    // stage U at base rate, clamped rows (plain layout, no swizzle)
    if (STAGE == 0) {
        const float* xb = Xf + (size_t)b * T * 96;
        for (int idx = tid; idx < UROWS * 12; idx += 256) {
            int r = idx / 12, q = idx - r * 12;
            int rg = rb0 + r; rg = rg < 0 ? 0 : (rg > T - 1 ? T - 1 : rg);
            const float* src = xb + (size_t)rg * 96 + q * 8;
            float4 a = *(const float4*)src;
            float4 c2 = *(const float4*)(src + 4);
            u32x4 v;
            v[0] = (u32)f2bf(a.x) | ((u32)f2bf(a.y) << 16);
            v[1] = (u32)f2bf(a.z) | ((u32)f2bf(a.w) << 16);
            v[2] = (u32)f2bf(c2.x) | ((u32)f2bf(c2.y) << 16);
            v[3] = (u32)f2bf(c2.z) | ((u32)f2bf(c2.w) << 16);
            *(u32x4*)(Ub + r * USTRB + q * 16) = v;
        }
    } else {
        const ushort_t* xb = Hbf + (size_t)b * T * 96;
        for (int idx = tid; idx < UROWS * 12; idx += 256) {
            int r = idx / 12, q = idx - r * 12;
            int rg = rb0 + r; rg = rg < 0 ? 0 : (rg > T - 1 ? T - 1 : rg);
            u32x4 v = *(const u32x4*)(xb + (size_t)rg * 96 + q * 8);
            *(u32x4*)(Ub + r * USTRB + q * 16) = v;
        }
    }
    __syncthreads();

    f32x4 acc[3][4];
#pragma unroll
    for (int m = 0; m < 3; ++m)
#pragma unroll
        for (int n = 0; n < 4; ++n) acc[m][n] = (f32x4){0.f, 0.f, 0.f, 0.f};

    const int rowbase = 64 * nq + (lane & 15);
    const int og16 = (lane >> 4) * 16;

#pragma unroll
    for (int j = 0; j < 9; ++j) {
        const ushort_t* wj = wgl + (size_t)j * 18432;
        bf16x8 aj[9];
#pragma unroll
        for (int q = 0; q < 9; ++q)
            aj[q] = *(const bf16x8*)(wj + q * 512);

        const int bj = (rowbase + j) * USTRB;
#pragma unroll
        for (int cb = 0; cb < 3; ++cb) {
            const int off0 = bj + cb * 64 + og16;
            bf16x8 bfr[4];
#pragma unroll
            for (int n = 0; n < 4; ++n)
                bfr[n] = *(const bf16x8*)(Ub + off0 + n * 16 * USTRB);
            __builtin_amdgcn_s_setprio(1);
#pragma unroll
            for (int m = 0; m < 3; ++m)
#pragma unroll
                for (int n = 0; n < 4; ++n)
                    acc[m][n] = __builtin_amdgcn_mfma_f32_16x16x32_bf16(aj[cb * 3 + m], bfr[n], acc[m][n], 0, 0, 0);
            __builtin_amdgcn_s_setprio(0);
        }
    }

    // ---------------- epilogue: LDS transpose -> coalesced stores --------------
    const int T2 = 2 * T;
    const int t0 = tg * 2 * NBB;          // 256 output t per block
    const int og4 = (lane >> 4) * 4;

    __syncthreads();   // all B-frag reads done before Ub reuse

    if (STAGE == 0) {
        ushort_t* L0 = (ushort_t*)Ub;     // [256 t][48 ch] bf16, stride 104 B
#pragma unroll
        for (int m = 0; m < 3; ++m) {
            int obase = mh * 48 + m * 16 + og4;
            float addv[4];
#pragma unroll
            for (int rr = 0; rr < 4; ++rr) addv[rr] = ADD[b * 96 + obase + rr];
#pragma unroll
            for (int n = 0; n < 4; ++n) {
                int tl = 2 * (rowbase + 16 * n) + phase;   // 0..255
                int tgl = t0 + tl;
                ushort_t pk[4];
#pragma unroll
                for (int rr = 0; rr < 4; ++rr) {
                    float v = acc[m][n][rr] + addv[rr];
                    if (tgl < 7)                   v -= CF[(b * 7 + tgl) * 96 + obase + rr];
                    if (tgl >= T2 - 7 && tgl < T2) v -= CB[(b * 7 + tgl - (T2 - 7)) * 96 + obase + rr];
                    v = v > 0.f ? v : 0.2f * v;
                    pk[rr] = f2bf(v);
                }
                uint2 w2;
                w2.x = (u32)pk[0] | ((u32)pk[1] << 16);
                w2.y = (u32)pk[2] | ((u32)pk[3] << 16);
                *(uint2*)((char*)L0 + tl * 104 + (m * 16 + og4) * 2) = w2;
            }
        }
        __syncthreads();
        for (int g = tid; g < 256 * 6; g += 256) {   // 256 t x 6 seg of 16 B
            int row = g / 6, col = g % 6;
            int t = t0 + row;
            if (t < T2) {
                u32x4 v = *(const u32x4*)((char*)L0 + row * 104 + col * 16);
                *(u32x4*)((char*)Hout + ((size_t)(b * T2 + t) * 96 + mh * 48) * 2 + col * 16) = v;
            }
        }
    } else {
        const int TO = T2 - 1;            // 4095
        float* L1 = (float*)Ub;           // [16 o][LSTR1 f32] per m-chunk
#pragma unroll
        for (int m = 0; m < 3; ++m) {
            int obase = mh * 48 + m * 16 + og4;
            float addv[4];
#pragma unroll
            for (int rr = 0; rr < 4; ++rr) addv[rr] = ADD[b * 96 + obase + rr];
#pragma unroll
            for (int n = 0; n < 4; ++n) {
                int tl = 2 * (rowbase + 16 * n) + phase;
                int tgl = t0 + tl;
#pragma unroll
                for (int rr = 0; rr < 4; ++rr) {
                    float v = acc[m][n][rr] + addv[rr];
                    if (tgl < 7)                   v -= CF[(b * 7 + tgl) * 96 + obase + rr];
                    if (tgl >= T2 - 7 && tgl < T2) v -= CB[(b * 7 + tgl - (T2 - 7)) * 96 + obase + rr];
                    L1[(og4 + rr) * LSTR1 + tl] = v;
                }
            }
            __syncthreads();
            for (int g = tid; g < 4096; g += 256) {  // 16 o-rows x 256 cols
                int row = g >> 8, col = g & 255;
                int t = t0 + col;
                if (t < TO) {
                    int o_g = mh * 48 + m * 16 + row;
                    Fout[((size_t)(b * 96 + o_g)) * TO + t] = L1[row * LSTR1 + col];
                }
            }
            __syncthreads();
        }
    }
}

extern "C" void kernel_launch(void* const* d_in, const int* in_sizes, int n_in,
                              void* d_out, int out_size, void* d_ws, size_t ws_size,
                              hipStream_t stream)
{
    const float* x       = (const float*)d_in[0];
    const float* offset0 = (const float*)d_in[1];
    const float* offset1 = (const float*)d_in[2];
    const float* conv_w0 = (const float*)d_in[5];
    const float* conv_b0 = (const float*)d_in[6];
    const float* conv_w1 = (const float*)d_in[7];
    const float* conv_b1 = (const float*)d_in[8];
    const float* off_w0  = (const float*)d_in[9];
    const float* off_b0  = (const float*)d_in[10];
    const float* off_w1  = (const float*)d_in[11];
    const float* off_b1  = (const float*)d_in[12];
    const float* cmask0  = (const float*)d_in[13];
    const float* cmask1  = (const float*)d_in[14];
    const float* omask0  = (const float*)d_in[15];
    const float* omask1  = (const float*)d_in[16];

    char* ws = (char*)d_ws;
    float*    Wplain = (float*)(ws);                  // 1,105,920
    ushort_t* Wp0    = (ushort_t*)(ws + 1105920);     // 331,776
    ushort_t* Wp1    = (ushort_t*)(ws + 1437696);     // 331,776
    float*    ADD0   = (float*)(ws + 1769472);        // 24,576
    float*    ADD1   = (float*)(ws + 1794048);        // 24,576
    float*    CF0    = (float*)(ws + 1818624);        // 172,032
    float*    CB0    = (float*)(ws + 1990656);        // 172,032
    float*    CF1    = (float*)(ws + 2162688);        // 172,032
    float*    CB1    = (float*)(ws + 2334720);        // 172,032
    float*    G0     = (float*)(ws + 2506752);        // 737,280
    float*    G1     = (float*)(ws + 3244032);        // 737,280
    ushort_t* H1     = (ushort_t*)(ws + 3981312);     // 25,165,824
    float* out = (float*)d_out;

    prepA<<<480, 64, 0, stream>>>(conv_w0, cmask0, conv_w1, cmask1,
                                  off_w0, off_b0, omask0, conv_b0, offset0,
                                  off_w1, off_b1, omask1, conv_b1, offset1,
                                  Wplain, ADD0, ADD1);
    prepBG<<<2016, 256, 0, stream>>>(Wplain, Wp0, Wp1, x, G0);
    prep_cfb<<<336, 256, 0, stream>>>(G0, CF0, CB0);

    conv_poly<0><<<1024, 256, LDS_TOTAL, stream>>>(x, nullptr, Wp0, ADD0, CF0, CB0,
                                                   H1, nullptr, 1024);
    prep_G1<<<720, 256, 0, stream>>>(Wplain + 138240, H1, G1);
    prep_cfb<<<336, 256, 0, stream>>>(G1, CF1, CB1);
    conv_poly<1><<<2048, 256, LDS_TOTAL, stream>>>(nullptr, H1, Wp1, ADD1, CF1, CB1,
                                                   nullptr, out, 2048);
}